// Round 4
// baseline (653.684 us; speedup 1.0000x reference)
//
#include <hip/hip_runtime.h>
#include <hip/hip_fp16.h>
#include <hip/hip_cooperative_groups.h>

namespace cg = cooperative_groups;

typedef __attribute__((ext_vector_type(8))) short bf16x8;
typedef __attribute__((ext_vector_type(4))) float f32x4;

static __device__ __forceinline__ float leaky(float v) { return v >= 0.f ? v : 0.01f * v; }

// pack fp32 -> (bf16 hi in bits[15:0], bf16 lo in bits[31:16]), both RNE
static __device__ __forceinline__ unsigned int packsplit(float v) {
    unsigned int u = __float_as_uint(v);
    unsigned int hi = (u + 0x7FFFu + ((u >> 16) & 1u)) >> 16;
    float hf = __uint_as_float(hi << 16);
    float lof = v - hf;
    unsigned int ul = __float_as_uint(lof);
    unsigned int lo = (ul + 0x7FFFu + ((ul >> 16) & 1u)) >> 16;
    return (hi & 0xFFFFu) | (lo << 16);
}

// ---------------- cooperative build: zero+prep+deg+scan+rowptr/dinv+fill ----------------
__global__ __launch_bounds__(256) void k_build(
    const float* __restrict__ x, const int* __restrict__ src, const int* __restrict__ dst,
    const float* __restrict__ W1, const float* __restrict__ W3, const float* __restrict__ fc1w,
    const float* __restrict__ fc2b,
    int* __restrict__ deg, int* __restrict__ cursor, int* __restrict__ part,
    int* __restrict__ bsum, int* __restrict__ rowptr, int* __restrict__ csr,
    float* __restrict__ dinv, __half* __restrict__ x16,
    unsigned int* __restrict__ W1T, unsigned int* __restrict__ W3T, unsigned int* __restrict__ F1p,
    float* __restrict__ out, int N, int E)
{
    cg::grid_group grid = cg::this_grid();
    __shared__ int s[256];
    const int gsz = gridDim.x * 256;
    const int gtid = blockIdx.x * 256 + threadIdx.x;

    // phase a: zero counters, init out, weight prep, x -> fp16
    for (int i = gtid; i < N; i += gsz) { deg[i] = 0; cursor[i] = 0; out[i] = fc2b[0]; }
    for (int i = gtid; i < 128 * 512; i += gsz) { int k = i >> 9, n = i & 511; W1T[(n << 7) | k] = packsplit(W1[i]); }
    for (int i = gtid; i < 512 * 128; i += gsz) { int k = i >> 7, n = i & 127; W3T[(n << 9) | k] = packsplit(W3[i]); }
    for (int i = gtid; i < 256 * 128; i += gsz) F1p[i] = packsplit(fc1w[i]);
    for (int i = gtid; i < N * 64; i += gsz) {
        float2 f = ((const float2*)x)[i];
        ((__half2*)x16)[i] = __floats2half2_rn(f.x, f.y);
    }
    grid.sync();
    // phase b: degree count
    for (int e = gtid; e < E; e += gsz) atomicAdd(&deg[dst[e]], 1);
    grid.sync();
    // phase c: per-block inclusive scan of deg -> part (exclusive), bsum
    const int nScan = (N + 255) >> 8;   // <= 256 required
    if (blockIdx.x < nScan) {
        int tx = threadIdx.x, i = blockIdx.x * 256 + tx;
        int v = (i < N) ? deg[i] : 0;
        s[tx] = v; __syncthreads();
        for (int off = 1; off < 256; off <<= 1) {
            int t = (tx >= off) ? s[tx - off] : 0; __syncthreads();
            s[tx] += t; __syncthreads();
        }
        if (i < N) part[i] = s[tx] - v;
        if (tx == 255) bsum[blockIdx.x] = s[255];
    }
    grid.sync();
    // phase d: scan block sums (block 0)
    if (blockIdx.x == 0) {
        int tx = threadIdx.x;
        int v = (tx < nScan) ? bsum[tx] : 0;
        s[tx] = v; __syncthreads();
        for (int off = 1; off < 256; off <<= 1) {
            int t = (tx >= off) ? s[tx - off] : 0; __syncthreads();
            s[tx] += t; __syncthreads();
        }
        if (tx < nScan) bsum[tx] = s[tx] - v;
    }
    grid.sync();
    // phase e: rowptr + dinv
    for (int i = gtid; i <= N; i += gsz) {
        if (i < N) { rowptr[i] = part[i] + bsum[i >> 8]; dinv[i] = rsqrtf((float)deg[i] + 1.0f); }
        else rowptr[N] = E;
    }
    grid.sync();
    // phase f: CSR fill
    for (int e = gtid; e < E; e += gsz) {
        int d = dst[e];
        int pos = atomicAdd(&cursor[d], 1);
        csr[rowptr[d] + pos] = src[e];
    }
}

// ---------------- gather aggregation (fp16 rows in, packed bf16 hi/lo out) ----------------
template <bool BIASACT>
__global__ __launch_bounds__(256) void k_gather(const __half* __restrict__ X,
                                                const int* __restrict__ rowptr,
                                                const int* __restrict__ csr,
                                                const float* __restrict__ dinv,
                                                const float* __restrict__ bias,
                                                unsigned int* __restrict__ outp, int N) {
    int wid = __builtin_amdgcn_readfirstlane((int)((blockIdx.x * 256 + threadIdx.x) >> 6));
    if (wid >= N) return;
    int lane = threadIdx.x & 63, c = lane * 2;
    float di = dinv[wid];
    float2 self = __half22float2(*(const __half2*)(X + (size_t)wid * 128 + c));
    float accx = self.x * di, accy = self.y * di;
    int k = rowptr[wid], end = rowptr[wid + 1];
    for (; k < end; k += 8) {
        int ss[8]; float ww[8];
        #pragma unroll
        for (int i = 0; i < 8; ++i) {
            int idx = k + i;
            bool v = idx < end;
            ss[i] = v ? csr[idx] : 0;
            ww[i] = v ? dinv[ss[i]] : 0.f;
        }
        #pragma unroll
        for (int i = 0; i < 8; ++i) {
            float2 f = __half22float2(*(const __half2*)(X + (size_t)ss[i] * 128 + c));
            accx += f.x * ww[i];
            accy += f.y * ww[i];
        }
    }
    accx *= di;
    accy *= di;
    if (BIASACT) {
        accx = leaky(accx + bias[c]);
        accy = leaky(accy + bias[c + 1]);
    }
    uint2 p;
    p.x = packsplit(accx);
    p.y = packsplit(accy);
    *(uint2*)(outp + (size_t)wid * 128 + c) = p;
}

// ---------------- MFMA GEMM (bf16 hi/lo x3) ----------------
// A: [M][K] packed u32; B: [Ntot][K] packed u32.
// MODE 0: C = A@B  -> fp16 out [M][Ntot]
// MODE 1: C = packsplit(leaky(A@B + bias)) -> u32 out [M][Ntot]
// MODE 2: atomicAdd(out[row], sum_col leaky(A@B + bias)[col] * w2[col])
template <int MODE>
__global__ __launch_bounds__(256, 2) void k_mgemm(const unsigned int* __restrict__ Ap,
                                                  const unsigned int* __restrict__ Bp,
                                                  const float* __restrict__ bias,
                                                  const float* __restrict__ w2,
                                                  void* __restrict__ Cout,
                                                  int M, int Ntot, int K) {
    __shared__ __align__(16) unsigned short smem[16384]; // Ahi/Alo/Bhi/Blo, each [128][32] bf16
    unsigned short* Ahi = smem;
    unsigned short* Alo = smem + 4096;
    unsigned short* Bhi = smem + 8192;
    unsigned short* Blo = smem + 12288;

    const int tid = threadIdx.x, lane = tid & 63, wid = tid >> 6;
    const int wr = wid >> 1, wc = wid & 1;
    const int nbx = Ntot >> 7;
    const int bx = blockIdx.x % nbx, by = blockIdx.x / nbx;
    const int m0 = by * 128, n0 = bx * 128;
    const int rl = lane >> 3, cl = lane & 7;

    f32x4 acc[4][4] = {};
    uint4 rA[4], rB[4];

    auto issue = [&](int k0) {
        #pragma unroll
        for (int j = 0; j < 4; ++j) {
            int r = wid * 32 + j * 8 + rl;
            int ga = m0 + r; ga = (ga < M) ? ga : (M - 1);
            rA[j] = *(const uint4*)(Ap + (size_t)ga * K + k0 + cl * 4);
            rB[j] = *(const uint4*)(Bp + (size_t)(n0 + r) * K + k0 + cl * 4);
        }
    };
    auto commit = [&]() {
        #pragma unroll
        for (int j = 0; j < 4; ++j) {
            int r = wid * 32 + j * 8 + rl;
            int off = r * 32 + cl * 4;
            uint4 v = rA[j];
            uint2 h, l;
            h.x = (v.x & 0xFFFFu) | (v.y << 16);
            h.y = (v.z & 0xFFFFu) | (v.w << 16);
            l.x = (v.x >> 16) | (v.y & 0xFFFF0000u);
            l.y = (v.z >> 16) | (v.w & 0xFFFF0000u);
            *(uint2*)(Ahi + off) = h;
            *(uint2*)(Alo + off) = l;
            v = rB[j];
            h.x = (v.x & 0xFFFFu) | (v.y << 16);
            h.y = (v.z & 0xFFFFu) | (v.w << 16);
            l.x = (v.x >> 16) | (v.y & 0xFFFF0000u);
            l.y = (v.z >> 16) | (v.w & 0xFFFF0000u);
            *(uint2*)(Bhi + off) = h;
            *(uint2*)(Blo + off) = l;
        }
    };
    auto rdfrag = [&](const unsigned short* base, int rbase) -> bf16x8 {
        int row = rbase + (lane & 15);
        return *(const bf16x8*)(base + row * 32 + (lane >> 4) * 8);
    };

    const int nsteps = K >> 5;
    issue(0);
    commit();
    __syncthreads();
    for (int t = 0; t < nsteps; ++t) {
        if (t + 1 < nsteps) issue((t + 1) << 5);
        bf16x8 ah[4], al[4], bh[4], bl[4];
        #pragma unroll
        for (int i = 0; i < 4; ++i) {
            ah[i] = rdfrag(Ahi, wr * 64 + i * 16);
            al[i] = rdfrag(Alo, wr * 64 + i * 16);
            bh[i] = rdfrag(Bhi, wc * 64 + i * 16);
            bl[i] = rdfrag(Blo, wc * 64 + i * 16);
        }
        #pragma unroll
        for (int i = 0; i < 4; ++i) {
            #pragma unroll
            for (int n = 0; n < 4; ++n) {
                acc[i][n] = __builtin_amdgcn_mfma_f32_16x16x32_bf16(ah[i], bh[n], acc[i][n], 0, 0, 0);
                acc[i][n] = __builtin_amdgcn_mfma_f32_16x16x32_bf16(al[i], bh[n], acc[i][n], 0, 0, 0);
                acc[i][n] = __builtin_amdgcn_mfma_f32_16x16x32_bf16(ah[i], bl[n], acc[i][n], 0, 0, 0);
            }
        }
        __syncthreads();
        if (t + 1 < nsteps) { commit(); __syncthreads(); }
    }

    if (MODE == 0) {
        __half* C = (__half*)Cout;
        #pragma unroll
        for (int i = 0; i < 4; ++i) {
            #pragma unroll
            for (int j = 0; j < 4; ++j) {
                int row = m0 + wr * 64 + i * 16 + (lane >> 4) * 4 + j;
                if (row < M) {
                    #pragma unroll
                    for (int n = 0; n < 4; ++n) {
                        int col = n0 + wc * 64 + n * 16 + (lane & 15);
                        C[(size_t)row * Ntot + col] = __float2half(acc[i][n][j]);
                    }
                }
            }
        }
    } else if (MODE == 1) {
        unsigned int* C = (unsigned int*)Cout;
        #pragma unroll
        for (int i = 0; i < 4; ++i) {
            #pragma unroll
            for (int j = 0; j < 4; ++j) {
                int row = m0 + wr * 64 + i * 16 + (lane >> 4) * 4 + j;
                if (row < M) {
                    #pragma unroll
                    for (int n = 0; n < 4; ++n) {
                        int col = n0 + wc * 64 + n * 16 + (lane & 15);
                        float v = leaky(acc[i][n][j] + bias[col]);
                        C[(size_t)row * Ntot + col] = packsplit(v);
                    }
                }
            }
        }
    } else {
        float* C = (float*)Cout;
        #pragma unroll
        for (int i = 0; i < 4; ++i) {
            #pragma unroll
            for (int j = 0; j < 4; ++j) {
                int row = m0 + wr * 64 + i * 16 + (lane >> 4) * 4 + j;
                float s = 0.f;
                #pragma unroll
                for (int n = 0; n < 4; ++n) {
                    int col = n0 + wc * 64 + n * 16 + (lane & 15);
                    float v = leaky(acc[i][n][j] + bias[col]);
                    s += v * w2[col];
                }
                s += __shfl_xor(s, 8);
                s += __shfl_xor(s, 4);
                s += __shfl_xor(s, 2);
                s += __shfl_xor(s, 1);
                if ((lane & 15) == 0 && row < M) atomicAdd(&C[row], s);
            }
        }
    }
}

extern "C" void kernel_launch(void* const* d_in, const int* in_sizes, int n_in,
                              void* d_out, int out_size, void* d_ws, size_t ws_size,
                              hipStream_t stream) {
    const float* x    = (const float*)d_in[0];
    const int*   ei   = (const int*)d_in[1];
    const float* W1   = (const float*)d_in[2];
    const float* b1   = (const float*)d_in[3];
    const float* W3   = (const float*)d_in[4];
    const float* b3   = (const float*)d_in[5];
    const float* fc1w = (const float*)d_in[6];
    const float* fc1b = (const float*)d_in[7];
    const float* fc2w = (const float*)d_in[8];
    const float* fc2b = (const float*)d_in[9];
    float* out = (float*)d_out;

    int N = in_sizes[0] / 128;   // 50000
    int E = in_sizes[1] / 2;     // 800000
    const int* src = ei;
    const int* dst = ei + E;

    char* ws = (char*)d_ws;
    size_t off = 0;
    auto alloc = [&](size_t bytes) { void* p = ws + off; off += (bytes + 255) & ~255ull; return p; };
    int*   deg    = (int*)alloc((size_t)N * 4);
    int*   cursor = (int*)alloc((size_t)N * 4);
    int*   part   = (int*)alloc((size_t)N * 4);
    int*   bsum   = (int*)alloc(256 * 4);
    int*   rowptr = (int*)alloc((size_t)(N + 1) * 4);
    int*   csr    = (int*)alloc((size_t)E * 4);
    float* dinv   = (float*)alloc((size_t)N * 4);
    __half* x16   = (__half*)alloc((size_t)N * 128 * 2);
    unsigned int* A1p = (unsigned int*)alloc((size_t)N * 128 * 4);
    unsigned int* H1p = (unsigned int*)alloc((size_t)N * 512 * 4);
    __half*       t2  = (__half*)alloc((size_t)N * 128 * 2);
    unsigned int* A3p = (unsigned int*)alloc((size_t)N * 128 * 4);
    unsigned int* W1T = (unsigned int*)alloc((size_t)512 * 128 * 4);
    unsigned int* W3T = (unsigned int*)alloc((size_t)128 * 512 * 4);
    unsigned int* F1p = (unsigned int*)alloc((size_t)256 * 128 * 4);
    (void)ws_size; (void)n_in; (void)out_size;

    const int MB128 = (N + 127) / 128;  // 391
    dim3 blk(256);

    // 1) cooperative build: zero + weight prep + x16 + degree + scan + rowptr/dinv + fill
    {
        void* args[] = { (void*)&x, (void*)&src, (void*)&dst, (void*)&W1, (void*)&W3,
                         (void*)&fc1w, (void*)&fc2b,
                         (void*)&deg, (void*)&cursor, (void*)&part, (void*)&bsum,
                         (void*)&rowptr, (void*)&csr, (void*)&dinv, (void*)&x16,
                         (void*)&W1T, (void*)&W3T, (void*)&F1p, (void*)&out,
                         (void*)&N, (void*)&E };
        hipLaunchCooperativeKernel((void*)k_build, dim3(512), blk, args, 0, stream);
    }

    // 2) agg1 = Agg(x16) -> packed [N,128]
    k_gather<false><<<(N * 64 + 255) / 256, blk, 0, stream>>>(x16, rowptr, csr, dinv, nullptr, A1p, N);

    // 3) h1 = leaky(agg1 @ W1 + b1) -> packed [N,512]
    k_mgemm<1><<<MB128 * 4, blk, 0, stream>>>(A1p, W1T, b1, nullptr, H1p, N, 512, 128);

    // 4) t2 = h1 @ W3 -> fp16 [N,128]
    k_mgemm<0><<<MB128 * 1, blk, 0, stream>>>(H1p, W3T, nullptr, nullptr, t2, N, 128, 512);

    // 5) h2 = leaky(Agg(t2) + b3) -> packed [N,128]
    k_gather<true><<<(N * 64 + 255) / 256, blk, 0, stream>>>(t2, rowptr, csr, dinv, b3, A3p, N);

    // 6) out = leaky(h2 @ fc1_w^T + fc1_b) @ fc2_w^T + fc2_b  (fc2 fused, atomic partials)
    k_mgemm<2><<<MB128 * 2, blk, 0, stream>>>(A3p, F1p, fc1b, fc2w, out, N, 256, 128);
}

// Round 5
// 367.230 us; speedup vs baseline: 1.7800x; 1.7800x over previous
//
#include <hip/hip_runtime.h>
#include <hip/hip_fp16.h>

typedef __attribute__((ext_vector_type(8))) short bf16x8;
typedef __attribute__((ext_vector_type(4))) float f32x4;

static __device__ __forceinline__ float leaky(float v) { return v >= 0.f ? v : 0.01f * v; }

// pack fp32 -> (bf16 hi in bits[15:0], bf16 lo in bits[31:16]), both RNE
static __device__ __forceinline__ unsigned int packsplit(float v) {
    unsigned int u = __float_as_uint(v);
    unsigned int hi = (u + 0x7FFFu + ((u >> 16) & 1u)) >> 16;
    float hf = __uint_as_float(hi << 16);
    float lof = v - hf;
    unsigned int ul = __float_as_uint(lof);
    unsigned int lo = (ul + 0x7FFFu + ((ul >> 16) & 1u)) >> 16;
    return (hi & 0xFFFFu) | (lo << 16);
}

// ---------------- fused prep: zero ctrs, out-init, weight pack, x->fp16 ----------------
__global__ __launch_bounds__(256) void k_prep_all(
    const float* __restrict__ x, const float* __restrict__ W1, const float* __restrict__ W3,
    const float* __restrict__ fc1w, const float* __restrict__ fc2b,
    int* __restrict__ deg, int* __restrict__ cursor, float* __restrict__ out,
    __half* __restrict__ x16,
    unsigned int* __restrict__ W1T, unsigned int* __restrict__ W3T, unsigned int* __restrict__ F1p,
    int N)
{
    const int gsz = gridDim.x * 256;
    const int gtid = blockIdx.x * 256 + threadIdx.x;
    float ob = fc2b[0];
    for (int i = gtid; i < N; i += gsz) { deg[i] = 0; cursor[i] = 0; out[i] = ob; }
    for (int i = gtid; i < 128 * 512; i += gsz) { int k = i >> 9, n = i & 511; W1T[(n << 7) | k] = packsplit(W1[i]); }
    for (int i = gtid; i < 512 * 128; i += gsz) { int k = i >> 7, n = i & 127; W3T[(n << 9) | k] = packsplit(W3[i]); }
    for (int i = gtid; i < 256 * 128; i += gsz) F1p[i] = packsplit(fc1w[i]);
    for (int i = gtid; i < N * 64; i += gsz) {
        float2 f = ((const float2*)x)[i];
        ((__half2*)x16)[i] = __floats2half2_rn(f.x, f.y);
    }
}

// ---------------- CSR build ----------------
__global__ __launch_bounds__(256) void k_deg(const int* __restrict__ dst, int* __restrict__ deg, int E) {
    int e = blockIdx.x * 256 + threadIdx.x;
    if (e < E) atomicAdd(&deg[dst[e]], 1);
}

__global__ __launch_bounds__(256) void k_scan1(const int* __restrict__ deg, int* __restrict__ part,
                                               int* __restrict__ bsum, int n) {
    __shared__ int s[256];
    int tx = threadIdx.x, i = blockIdx.x * 256 + tx;
    int v = (i < n) ? deg[i] : 0;
    s[tx] = v; __syncthreads();
    for (int off = 1; off < 256; off <<= 1) {
        int t = (tx >= off) ? s[tx - off] : 0;
        __syncthreads();
        s[tx] += t;
        __syncthreads();
    }
    if (i < n) part[i] = s[tx] - v;
    if (tx == 255) bsum[blockIdx.x] = s[255];
}

__global__ __launch_bounds__(256) void k_scan2(int* __restrict__ bsum, int nb) {
    __shared__ int s[256];
    int tx = threadIdx.x;
    int v = (tx < nb) ? bsum[tx] : 0;
    s[tx] = v; __syncthreads();
    for (int off = 1; off < 256; off <<= 1) {
        int t = (tx >= off) ? s[tx - off] : 0;
        __syncthreads();
        s[tx] += t;
        __syncthreads();
    }
    if (tx < nb) bsum[tx] = s[tx] - v;
}

// rowptr + dinv fused
__global__ __launch_bounds__(256) void k_scan3(const int* __restrict__ part, const int* __restrict__ bsum,
                                               const int* __restrict__ deg,
                                               int* __restrict__ rowptr, float* __restrict__ dinv,
                                               int n, int E) {
    int i = blockIdx.x * 256 + threadIdx.x;
    if (i < n) {
        rowptr[i] = part[i] + bsum[i >> 8];
        dinv[i] = rsqrtf((float)deg[i] + 1.0f);
    } else if (i == n) rowptr[n] = E;
}

__global__ __launch_bounds__(256) void k_fill(const int* __restrict__ src, const int* __restrict__ dst,
                                              const int* __restrict__ rowptr, int* __restrict__ cursor,
                                              int* __restrict__ csr, int E) {
    int e = blockIdx.x * 256 + threadIdx.x;
    if (e >= E) return;
    int d = dst[e];
    int pos = atomicAdd(&cursor[d], 1);
    csr[rowptr[d] + pos] = src[e];
}

// ---------------- gather aggregation (fp16 rows in, packed bf16 hi/lo out) ----------------
template <bool BIASACT>
__global__ __launch_bounds__(256) void k_gather(const __half* __restrict__ X,
                                                const int* __restrict__ rowptr,
                                                const int* __restrict__ csr,
                                                const float* __restrict__ dinv,
                                                const float* __restrict__ bias,
                                                unsigned int* __restrict__ outp, int N) {
    int wid = __builtin_amdgcn_readfirstlane((int)((blockIdx.x * 256 + threadIdx.x) >> 6));
    if (wid >= N) return;
    int lane = threadIdx.x & 63, c = lane * 2;
    float di = dinv[wid];
    float2 self = __half22float2(*(const __half2*)(X + (size_t)wid * 128 + c));
    float accx = self.x * di, accy = self.y * di;
    int k = rowptr[wid], end = rowptr[wid + 1];
    for (; k < end; k += 8) {
        int ss[8]; float ww[8];
        #pragma unroll
        for (int i = 0; i < 8; ++i) {
            int idx = k + i;
            bool v = idx < end;
            ss[i] = v ? csr[idx] : 0;
            ww[i] = v ? dinv[ss[i]] : 0.f;
        }
        #pragma unroll
        for (int i = 0; i < 8; ++i) {
            float2 f = __half22float2(*(const __half2*)(X + (size_t)ss[i] * 128 + c));
            accx += f.x * ww[i];
            accy += f.y * ww[i];
        }
    }
    accx *= di;
    accy *= di;
    if (BIASACT) {
        accx = leaky(accx + bias[c]);
        accy = leaky(accy + bias[c + 1]);
    }
    uint2 p;
    p.x = packsplit(accx);
    p.y = packsplit(accy);
    *(uint2*)(outp + (size_t)wid * 128 + c) = p;
}

// ---------------- MFMA GEMM (bf16 hi/lo x3) ----------------
// A: [M][K] packed u32; B: [Ntot][K] packed u32.
// MODE 0: C = A@B  -> fp16 out [M][Ntot]
// MODE 1: C = packsplit(leaky(A@B + bias)) -> u32 out [M][Ntot]
// MODE 2: atomicAdd(out[row], sum_col leaky(A@B + bias)[col] * w2[col])
template <int MODE>
__global__ __launch_bounds__(256, 2) void k_mgemm(const unsigned int* __restrict__ Ap,
                                                  const unsigned int* __restrict__ Bp,
                                                  const float* __restrict__ bias,
                                                  const float* __restrict__ w2,
                                                  void* __restrict__ Cout,
                                                  int M, int Ntot, int K) {
    __shared__ __align__(16) unsigned short smem[16384]; // Ahi/Alo/Bhi/Blo, each [128][32] bf16
    unsigned short* Ahi = smem;
    unsigned short* Alo = smem + 4096;
    unsigned short* Bhi = smem + 8192;
    unsigned short* Blo = smem + 12288;

    const int tid = threadIdx.x, lane = tid & 63, wid = tid >> 6;
    const int wr = wid >> 1, wc = wid & 1;
    const int nbx = Ntot >> 7;
    const int bx = blockIdx.x % nbx, by = blockIdx.x / nbx;
    const int m0 = by * 128, n0 = bx * 128;
    const int rl = lane >> 3, cl = lane & 7;

    f32x4 acc[4][4] = {};
    uint4 rA[4], rB[4];

    auto issue = [&](int k0) {
        #pragma unroll
        for (int j = 0; j < 4; ++j) {
            int r = wid * 32 + j * 8 + rl;
            int ga = m0 + r; ga = (ga < M) ? ga : (M - 1);
            rA[j] = *(const uint4*)(Ap + (size_t)ga * K + k0 + cl * 4);
            rB[j] = *(const uint4*)(Bp + (size_t)(n0 + r) * K + k0 + cl * 4);
        }
    };
    auto commit = [&]() {
        #pragma unroll
        for (int j = 0; j < 4; ++j) {
            int r = wid * 32 + j * 8 + rl;
            int off = r * 32 + cl * 4;
            uint4 v = rA[j];
            uint2 h, l;
            h.x = (v.x & 0xFFFFu) | (v.y << 16);
            h.y = (v.z & 0xFFFFu) | (v.w << 16);
            l.x = (v.x >> 16) | (v.y & 0xFFFF0000u);
            l.y = (v.z >> 16) | (v.w & 0xFFFF0000u);
            *(uint2*)(Ahi + off) = h;
            *(uint2*)(Alo + off) = l;
            v = rB[j];
            h.x = (v.x & 0xFFFFu) | (v.y << 16);
            h.y = (v.z & 0xFFFFu) | (v.w << 16);
            l.x = (v.x >> 16) | (v.y & 0xFFFF0000u);
            l.y = (v.z >> 16) | (v.w & 0xFFFF0000u);
            *(uint2*)(Bhi + off) = h;
            *(uint2*)(Blo + off) = l;
        }
    };
    auto rdfrag = [&](const unsigned short* base, int rbase) -> bf16x8 {
        int row = rbase + (lane & 15);
        return *(const bf16x8*)(base + row * 32 + (lane >> 4) * 8);
    };

    const int nsteps = K >> 5;
    issue(0);
    commit();
    __syncthreads();
    for (int t = 0; t < nsteps; ++t) {
        if (t + 1 < nsteps) issue((t + 1) << 5);
        bf16x8 ah[4], al[4], bh[4], bl[4];
        #pragma unroll
        for (int i = 0; i < 4; ++i) {
            ah[i] = rdfrag(Ahi, wr * 64 + i * 16);
            al[i] = rdfrag(Alo, wr * 64 + i * 16);
            bh[i] = rdfrag(Bhi, wc * 64 + i * 16);
            bl[i] = rdfrag(Blo, wc * 64 + i * 16);
        }
        #pragma unroll
        for (int i = 0; i < 4; ++i) {
            #pragma unroll
            for (int n = 0; n < 4; ++n) {
                acc[i][n] = __builtin_amdgcn_mfma_f32_16x16x32_bf16(ah[i], bh[n], acc[i][n], 0, 0, 0);
                acc[i][n] = __builtin_amdgcn_mfma_f32_16x16x32_bf16(al[i], bh[n], acc[i][n], 0, 0, 0);
                acc[i][n] = __builtin_amdgcn_mfma_f32_16x16x32_bf16(ah[i], bl[n], acc[i][n], 0, 0, 0);
            }
        }
        __syncthreads();
        if (t + 1 < nsteps) { commit(); __syncthreads(); }
    }

    if (MODE == 0) {
        __half* C = (__half*)Cout;
        #pragma unroll
        for (int i = 0; i < 4; ++i) {
            #pragma unroll
            for (int j = 0; j < 4; ++j) {
                int row = m0 + wr * 64 + i * 16 + (lane >> 4) * 4 + j;
                if (row < M) {
                    #pragma unroll
                    for (int n = 0; n < 4; ++n) {
                        int col = n0 + wc * 64 + n * 16 + (lane & 15);
                        C[(size_t)row * Ntot + col] = __float2half(acc[i][n][j]);
                    }
                }
            }
        }
    } else if (MODE == 1) {
        unsigned int* C = (unsigned int*)Cout;
        #pragma unroll
        for (int i = 0; i < 4; ++i) {
            #pragma unroll
            for (int j = 0; j < 4; ++j) {
                int row = m0 + wr * 64 + i * 16 + (lane >> 4) * 4 + j;
                if (row < M) {
                    #pragma unroll
                    for (int n = 0; n < 4; ++n) {
                        int col = n0 + wc * 64 + n * 16 + (lane & 15);
                        float v = leaky(acc[i][n][j] + bias[col]);
                        C[(size_t)row * Ntot + col] = packsplit(v);
                    }
                }
            }
        }
    } else {
        float* C = (float*)Cout;
        #pragma unroll
        for (int i = 0; i < 4; ++i) {
            #pragma unroll
            for (int j = 0; j < 4; ++j) {
                int row = m0 + wr * 64 + i * 16 + (lane >> 4) * 4 + j;
                float s = 0.f;
                #pragma unroll
                for (int n = 0; n < 4; ++n) {
                    int col = n0 + wc * 64 + n * 16 + (lane & 15);
                    float v = leaky(acc[i][n][j] + bias[col]);
                    s += v * w2[col];
                }
                s += __shfl_xor(s, 8);
                s += __shfl_xor(s, 4);
                s += __shfl_xor(s, 2);
                s += __shfl_xor(s, 1);
                if ((lane & 15) == 0 && row < M) atomicAdd(&C[row], s);
            }
        }
    }
}

extern "C" void kernel_launch(void* const* d_in, const int* in_sizes, int n_in,
                              void* d_out, int out_size, void* d_ws, size_t ws_size,
                              hipStream_t stream) {
    const float* x    = (const float*)d_in[0];
    const int*   ei   = (const int*)d_in[1];
    const float* W1   = (const float*)d_in[2];
    const float* b1   = (const float*)d_in[3];
    const float* W3   = (const float*)d_in[4];
    const float* b3   = (const float*)d_in[5];
    const float* fc1w = (const float*)d_in[6];
    const float* fc1b = (const float*)d_in[7];
    const float* fc2w = (const float*)d_in[8];
    const float* fc2b = (const float*)d_in[9];
    float* out = (float*)d_out;

    int N = in_sizes[0] / 128;   // 50000
    int E = in_sizes[1] / 2;     // 800000
    const int* src = ei;
    const int* dst = ei + E;

    char* ws = (char*)d_ws;
    size_t off = 0;
    auto alloc = [&](size_t bytes) { void* p = ws + off; off += (bytes + 255) & ~255ull; return p; };
    int*   deg    = (int*)alloc((size_t)N * 4);
    int*   cursor = (int*)alloc((size_t)N * 4);
    int*   part   = (int*)alloc((size_t)N * 4);
    int*   bsum   = (int*)alloc(256 * 4);
    int*   rowptr = (int*)alloc((size_t)(N + 1) * 4);
    int*   csr    = (int*)alloc((size_t)E * 4);
    float* dinv   = (float*)alloc((size_t)N * 4);
    __half* x16   = (__half*)alloc((size_t)N * 128 * 2);
    unsigned int* A1p = (unsigned int*)alloc((size_t)N * 128 * 4);
    unsigned int* H1p = (unsigned int*)alloc((size_t)N * 512 * 4);
    __half*       t2  = (__half*)alloc((size_t)N * 128 * 2);
    unsigned int* A3p = (unsigned int*)alloc((size_t)N * 128 * 4);
    unsigned int* W1T = (unsigned int*)alloc((size_t)512 * 128 * 4);
    unsigned int* W3T = (unsigned int*)alloc((size_t)128 * 512 * 4);
    unsigned int* F1p = (unsigned int*)alloc((size_t)256 * 128 * 4);
    (void)ws_size; (void)n_in; (void)out_size;

    const int MB128 = (N + 127) / 128;  // 391
    const int nb = (N + 255) / 256;
    dim3 blk(256);

    // 1) fused prep (independent work, one launch)
    k_prep_all<<<1024, blk, 0, stream>>>(x, W1, W3, fc1w, fc2b, deg, cursor, out, x16, W1T, W3T, F1p, N);

    // 2) CSR build
    k_deg<<<(E + 255) / 256, blk, 0, stream>>>(dst, deg, E);
    k_scan1<<<nb, blk, 0, stream>>>(deg, part, bsum, N);
    k_scan2<<<1, blk, 0, stream>>>(bsum, nb);
    k_scan3<<<(N + 256) / 256, blk, 0, stream>>>(part, bsum, deg, rowptr, dinv, N, E);
    k_fill<<<(E + 255) / 256, blk, 0, stream>>>(src, dst, rowptr, cursor, csr, E);

    // 3) agg1 = Agg(x16) -> packed [N,128]
    k_gather<false><<<(N * 64 + 255) / 256, blk, 0, stream>>>(x16, rowptr, csr, dinv, nullptr, A1p, N);

    // 4) h1 = leaky(agg1 @ W1 + b1) -> packed [N,512]
    k_mgemm<1><<<MB128 * 4, blk, 0, stream>>>(A1p, W1T, b1, nullptr, H1p, N, 512, 128);

    // 5) t2 = h1 @ W3 -> fp16 [N,128]
    k_mgemm<0><<<MB128 * 1, blk, 0, stream>>>(H1p, W3T, nullptr, nullptr, t2, N, 128, 512);

    // 6) h2 = leaky(Agg(t2) + b3) -> packed [N,128]
    k_gather<true><<<(N * 64 + 255) / 256, blk, 0, stream>>>(t2, rowptr, csr, dinv, b3, A3p, N);

    // 7) out = leaky(h2 @ fc1_w^T + fc1_b) @ fc2_w^T + fc2_b  (fc2 fused, atomic partials)
    k_mgemm<2><<<MB128 * 2, blk, 0, stream>>>(A3p, F1p, fc1b, fc2w, out, N, 256, 128);
}